// Round 2
// 655.235 us; speedup vs baseline: 1.0336x; 1.0336x over previous
//
#include <hip/hip_runtime.h>
#include <math.h>

// FlowMatching: out = t * gaussian_blur(x, sigma(t)) + (1-t) * x
// x: (128, 3, 512, 512) fp32, t: (128,) fp32
// sigma = 0.1 + 0.9*t ; K=9 taps (R=4), separable, zero padding.
//
// V2 structure: single 72x(stride 76) LDS buffer, horizontal pass done
// IN-PLACE (read phase / barrier / write phase -> race-free without relying
// on compiler ordering), vertical pass thread-coarsened 4 rows/thread.
// 21888 B LDS -> 7 blocks/CU (was 39168 B -> 4 blocks/CU).

#define TILE 64
#define HALO 4
#define KK 9
#define LW 72           // TILE + 2*HALO (data rows/cols)
#define LSTR 76         // LDS row stride: 76 % 32 == 12 -> odd-quad bank rotation
#define IMG 512

typedef float vfloat4 __attribute__((ext_vector_type(4)));  // native vec for nontemporal store

__global__ __launch_bounds__(256) void blur_blend_kernel(
    const float* __restrict__ x, const float* __restrict__ t,
    float* __restrict__ out)
{
    __shared__ __align__(16) float s[LW * LSTR];   // 21888 B

    const int tid   = threadIdx.x;        // 0..255
    const int bx    = blockIdx.x;         // tile col 0..7
    const int by    = blockIdx.y;         // tile row 0..7
    const int plane = blockIdx.z;         // 0..383  (b*3 + c)
    const int b     = plane / 3;

    // ---- per-batch 1D weights (uniform across block; computed redundantly)
    const float tb     = t[b];
    const float sigma  = 0.1f + tb * 0.9f;
    const float rmax   = ceilf(4.0f * sigma);
    const float inv2s2 = 1.0f / (2.0f * sigma * sigma);
    float w[KK];
    float wsum = 0.0f;
#pragma unroll
    for (int k = 0; k < KK; ++k) {
        float d = (float)(k - HALO);
        float v = (fabsf(d) <= rmax) ? expf(-d * d * inv2s2) : 0.0f;
        w[k] = v;
        wsum += v;
    }
    const float winv = 1.0f / wsum;
#pragma unroll
    for (int k = 0; k < KK; ++k) w[k] *= winv;

    const float* plane_in  = x   + (size_t)plane * (IMG * IMG);
    float*       plane_out = out + (size_t)plane * (IMG * IMG);
    const int gx0 = bx * TILE - HALO;
    const int gy0 = by * TILE - HALO;

    // ---- phase 1: global -> LDS, 72 rows x 18 quads
    for (int slot = tid; slot < LW * (LW / 4); slot += 256) {
        const int row = slot / (LW / 4);
        const int qc  = slot - row * (LW / 4);
        const int gy  = gy0 + row;
        const int gx  = gx0 + qc * 4;
        float4 v = make_float4(0.f, 0.f, 0.f, 0.f);
        if ((unsigned)gy < (unsigned)IMG) {
            if (gx >= 0 && gx + 3 < IMG) {
                v = *(const float4*)(plane_in + (size_t)gy * IMG + gx);
            } else {
                float* pv = &v.x;
#pragma unroll
                for (int j = 0; j < 4; ++j) {
                    const int g = gx + j;
                    if ((unsigned)g < (unsigned)IMG)
                        pv[j] = plane_in[(size_t)gy * IMG + g];
                }
            }
        }
        *(float4*)&s[row * LSTR + qc * 4] = v;
    }
    __syncthreads();

    // ---- phase 2 (s is READ-ONLY here):
    //   (a) save blend originals to registers (they get overwritten in phase 3)
    //   (b) horizontal 9-tap pass into registers. 288 tasks = 72 rows x 4
    //       groups of 16 cols; thread tid does task tid (+ task tid+256 if tid<32)
    const int r0 = (tid >> 4) * 4;        // output row group: 0,4,..,60
    const int qx = (tid & 15) * 4;        // output col quad : 0,4,..,60
    float4 orig[4];
#pragma unroll
    for (int o = 0; o < 4; ++o)
        orig[o] = *(const float4*)&s[(r0 + HALO + o) * LSTR + qx + HALO];

    const int hrow0 = tid >> 2;           // 0..63
    const int hc0   = (tid & 3) * 16;     // 0,16,32,48
    float h0[16];
    {
        float f[24];
#pragma unroll
        for (int q = 0; q < 6; ++q)
            *(float4*)&f[q * 4] = *(const float4*)&s[hrow0 * LSTR + hc0 + q * 4];
#pragma unroll
        for (int j = 0; j < 16; ++j) {
            float acc = 0.0f;
#pragma unroll
            for (int k = 0; k < KK; ++k) acc += w[k] * f[j + k];
            h0[j] = acc;
        }
    }
    const int hrow1 = (tid + 256) >> 2;   // rows 64..71
    const int hc1   = ((tid + 256) & 3) * 16;
    float h1[16];
    if (tid < 32) {
        float f[24];
#pragma unroll
        for (int q = 0; q < 6; ++q)
            *(float4*)&f[q * 4] = *(const float4*)&s[hrow1 * LSTR + hc1 + q * 4];
#pragma unroll
        for (int j = 0; j < 16; ++j) {
            float acc = 0.0f;
#pragma unroll
            for (int k = 0; k < KK; ++k) acc += w[k] * f[j + k];
            h1[j] = acc;
        }
    }
    __syncthreads();

    // ---- phase 3: write H results back into s (in-place, barrier-separated)
    //      H(row, c) for output col c in 0..63 stored at s[row][c+HALO]
#pragma unroll
    for (int q = 0; q < 4; ++q)
        *(float4*)&s[hrow0 * LSTR + hc0 + HALO + q * 4] = *(const float4*)&h0[q * 4];
    if (tid < 32) {
#pragma unroll
        for (int q = 0; q < 4; ++q)
            *(float4*)&s[hrow1 * LSTR + hc1 + HALO + q * 4] = *(const float4*)&h1[q * 4];
    }
    __syncthreads();

    // ---- phase 4: vertical 9-tap, 4 output rows per thread (12-row window),
    //      blend with register-held originals, nontemporal float4 store
    float4 acc[4];
#pragma unroll
    for (int o = 0; o < 4; ++o) acc[o] = make_float4(0.f, 0.f, 0.f, 0.f);
#pragma unroll
    for (int rr = 0; rr < 12; ++rr) {
        const float4 v = *(const float4*)&s[(r0 + rr) * LSTR + qx + HALO];
#pragma unroll
        for (int o = 0; o < 4; ++o) {
            const int k = rr - o;
            if (k >= 0 && k < KK) {
                acc[o].x += w[k] * v.x;
                acc[o].y += w[k] * v.y;
                acc[o].z += w[k] * v.z;
                acc[o].w += w[k] * v.w;
            }
        }
    }
    const float one_m_t = 1.0f - tb;
    const int gxout = bx * TILE + qx;
#pragma unroll
    for (int o = 0; o < 4; ++o) {
        vfloat4 res;
        res.x = tb * acc[o].x + one_m_t * orig[o].x;
        res.y = tb * acc[o].y + one_m_t * orig[o].y;
        res.z = tb * acc[o].z + one_m_t * orig[o].z;
        res.w = tb * acc[o].w + one_m_t * orig[o].w;
        const int gy = by * TILE + r0 + o;
        __builtin_nontemporal_store(res,
            (vfloat4*)(plane_out + (size_t)gy * IMG + gxout));
    }
}

extern "C" void kernel_launch(void* const* d_in, const int* in_sizes, int n_in,
                              void* d_out, int out_size, void* d_ws, size_t ws_size,
                              hipStream_t stream) {
    const float* x = (const float*)d_in[0];   // (128,3,512,512)
    const float* t = (const float*)d_in[1];   // (128,)
    float* out = (float*)d_out;
    dim3 grid(IMG / TILE, IMG / TILE, 128 * 3);  // (8, 8, 384)
    blur_blend_kernel<<<grid, 256, 0, stream>>>(x, t, out);
}

// Round 3
// 640.987 us; speedup vs baseline: 1.0566x; 1.0222x over previous
//
#include <hip/hip_runtime.h>
#include <math.h>

// FlowMatching: out = t * gaussian_blur(x, sigma(t)) + (1-t) * x
// x: (128, 3, 512, 512) fp32, t: (128,) fp32
// sigma = 0.1 + 0.9*t ; K=9 taps (R=4), separable, zero padding.
//
// V3: V2 (in-place 72x76 LDS, 21888 B -> 7 blocks/CU) plus:
//  - 1D grid with plane-per-XCD swizzle: each XCD owns whole planes, so
//    tile halos are L2-local (no cross-XCD HBM refetch).
//  - statically unrolled phase-1 staging (5x256 + 16 remainder) so all
//    global loads issue back-to-back before the LDS writes drain.

#define TILE 64
#define HALO 4
#define KK 9
#define LW 72           // TILE + 2*HALO (data rows/cols)
#define LSTR 76         // LDS row stride: 76 % 32 == 12 -> odd-quad bank rotation
#define IMG 512

typedef float vfloat4 __attribute__((ext_vector_type(4)));  // native vec for nontemporal store

__global__ __launch_bounds__(256) void blur_blend_kernel(
    const float* __restrict__ x, const float* __restrict__ t,
    float* __restrict__ out)
{
    __shared__ __align__(16) float s[LW * LSTR];   // 21888 B

    const int tid = threadIdx.x;          // 0..255

    // ---- plane-per-XCD swizzle (XCD = linear blockIdx % 8 round-robin):
    // n = 0..24575 ; xcd = n&7 ; c = n>>3 (0..3071)
    // plane = xcd + 8*(c>>6)  -> all 64 tiles of a plane on ONE XCD
    const int n      = blockIdx.x;
    const int xcd    = n & 7;
    const int c      = n >> 3;
    const int plane  = xcd + ((c >> 6) << 3);   // 0..383 (b*3 + ch)
    const int tileid = c & 63;
    const int bx     = tileid & 7;        // tile col 0..7
    const int by     = tileid >> 3;       // tile row 0..7
    const int b      = plane / 3;

    // ---- per-batch 1D weights (uniform across block; computed redundantly)
    const float tb     = t[b];
    const float sigma  = 0.1f + tb * 0.9f;
    const float rmax   = ceilf(4.0f * sigma);
    const float inv2s2 = 1.0f / (2.0f * sigma * sigma);
    float w[KK];
    float wsum = 0.0f;
#pragma unroll
    for (int k = 0; k < KK; ++k) {
        float d = (float)(k - HALO);
        float v = (fabsf(d) <= rmax) ? expf(-d * d * inv2s2) : 0.0f;
        w[k] = v;
        wsum += v;
    }
    const float winv = 1.0f / wsum;
#pragma unroll
    for (int k = 0; k < KK; ++k) w[k] *= winv;

    const float* plane_in  = x   + (size_t)plane * (IMG * IMG);
    float*       plane_out = out + (size_t)plane * (IMG * IMG);
    const int gx0 = bx * TILE - HALO;
    const int gy0 = by * TILE - HALO;

    // ---- phase 1: global -> LDS, 72 rows x 18 quads = 1296 slots
    //      static 5x256 unroll + 16-slot remainder for load pipelining
#pragma unroll
    for (int it = 0; it < 5; ++it) {
        const int slot = tid + it * 256;
        const int row = slot / (LW / 4);
        const int qc  = slot - row * (LW / 4);
        const int gy  = gy0 + row;
        const int gx  = gx0 + qc * 4;
        float4 v = make_float4(0.f, 0.f, 0.f, 0.f);
        if ((unsigned)gy < (unsigned)IMG) {
            if (gx >= 0 && gx + 3 < IMG) {
                v = *(const float4*)(plane_in + (size_t)gy * IMG + gx);
            } else {
                float* pv = &v.x;
#pragma unroll
                for (int j = 0; j < 4; ++j) {
                    const int g = gx + j;
                    if ((unsigned)g < (unsigned)IMG)
                        pv[j] = plane_in[(size_t)gy * IMG + g];
                }
            }
        }
        *(float4*)&s[row * LSTR + qc * 4] = v;
    }
    if (tid < 16) {
        const int slot = 1280 + tid;
        const int row = slot / (LW / 4);
        const int qc  = slot - row * (LW / 4);
        const int gy  = gy0 + row;
        const int gx  = gx0 + qc * 4;
        float4 v = make_float4(0.f, 0.f, 0.f, 0.f);
        if ((unsigned)gy < (unsigned)IMG) {
            if (gx >= 0 && gx + 3 < IMG) {
                v = *(const float4*)(plane_in + (size_t)gy * IMG + gx);
            } else {
                float* pv = &v.x;
#pragma unroll
                for (int j = 0; j < 4; ++j) {
                    const int g = gx + j;
                    if ((unsigned)g < (unsigned)IMG)
                        pv[j] = plane_in[(size_t)gy * IMG + g];
                }
            }
        }
        *(float4*)&s[row * LSTR + qc * 4] = v;
    }
    __syncthreads();

    // ---- phase 2 (s is READ-ONLY here):
    //   (a) save blend originals to registers (overwritten in phase 3)
    //   (b) horizontal 9-tap pass into registers. 288 tasks = 72 rows x 4
    //       groups of 16 cols; thread tid does task tid (+ tid+256 if tid<32)
    const int r0 = (tid >> 4) * 4;        // output row group: 0,4,..,60
    const int qx = (tid & 15) * 4;        // output col quad : 0,4,..,60
    float4 orig[4];
#pragma unroll
    for (int o = 0; o < 4; ++o)
        orig[o] = *(const float4*)&s[(r0 + HALO + o) * LSTR + qx + HALO];

    const int hrow0 = tid >> 2;           // 0..63
    const int hc0   = (tid & 3) * 16;     // 0,16,32,48
    float h0[16];
    {
        float f[24];
#pragma unroll
        for (int q = 0; q < 6; ++q)
            *(float4*)&f[q * 4] = *(const float4*)&s[hrow0 * LSTR + hc0 + q * 4];
#pragma unroll
        for (int j = 0; j < 16; ++j) {
            float acc = 0.0f;
#pragma unroll
            for (int k = 0; k < KK; ++k) acc += w[k] * f[j + k];
            h0[j] = acc;
        }
    }
    const int hrow1 = (tid + 256) >> 2;   // rows 64..71
    const int hc1   = ((tid + 256) & 3) * 16;
    float h1[16];
    if (tid < 32) {
        float f[24];
#pragma unroll
        for (int q = 0; q < 6; ++q)
            *(float4*)&f[q * 4] = *(const float4*)&s[hrow1 * LSTR + hc1 + q * 4];
#pragma unroll
        for (int j = 0; j < 16; ++j) {
            float acc = 0.0f;
#pragma unroll
            for (int k = 0; k < KK; ++k) acc += w[k] * f[j + k];
            h1[j] = acc;
        }
    }
    __syncthreads();

    // ---- phase 3: write H results back into s (in-place, barrier-separated)
    //      H(row, c) for output col c in 0..63 stored at s[row][c+HALO]
#pragma unroll
    for (int q = 0; q < 4; ++q)
        *(float4*)&s[hrow0 * LSTR + hc0 + HALO + q * 4] = *(const float4*)&h0[q * 4];
    if (tid < 32) {
#pragma unroll
        for (int q = 0; q < 4; ++q)
            *(float4*)&s[hrow1 * LSTR + hc1 + HALO + q * 4] = *(const float4*)&h1[q * 4];
    }
    __syncthreads();

    // ---- phase 4: vertical 9-tap, 4 output rows per thread (12-row window),
    //      blend with register-held originals, nontemporal float4 store
    float4 acc[4];
#pragma unroll
    for (int o = 0; o < 4; ++o) acc[o] = make_float4(0.f, 0.f, 0.f, 0.f);
#pragma unroll
    for (int rr = 0; rr < 12; ++rr) {
        const float4 v = *(const float4*)&s[(r0 + rr) * LSTR + qx + HALO];
#pragma unroll
        for (int o = 0; o < 4; ++o) {
            const int k = rr - o;
            if (k >= 0 && k < KK) {
                acc[o].x += w[k] * v.x;
                acc[o].y += w[k] * v.y;
                acc[o].z += w[k] * v.z;
                acc[o].w += w[k] * v.w;
            }
        }
    }
    const float one_m_t = 1.0f - tb;
    const int gxout = bx * TILE + qx;
#pragma unroll
    for (int o = 0; o < 4; ++o) {
        vfloat4 res;
        res.x = tb * acc[o].x + one_m_t * orig[o].x;
        res.y = tb * acc[o].y + one_m_t * orig[o].y;
        res.z = tb * acc[o].z + one_m_t * orig[o].z;
        res.w = tb * acc[o].w + one_m_t * orig[o].w;
        const int gy = by * TILE + r0 + o;
        __builtin_nontemporal_store(res,
            (vfloat4*)(plane_out + (size_t)gy * IMG + gxout));
    }
}

extern "C" void kernel_launch(void* const* d_in, const int* in_sizes, int n_in,
                              void* d_out, int out_size, void* d_ws, size_t ws_size,
                              hipStream_t stream) {
    const float* x = (const float*)d_in[0];   // (128,3,512,512)
    const float* t = (const float*)d_in[1];   // (128,)
    float* out = (float*)d_out;
    const int nblocks = (IMG / TILE) * (IMG / TILE) * 128 * 3;  // 24576
    blur_blend_kernel<<<dim3(nblocks), 256, 0, stream>>>(x, t, out);
}